// Round 13
// baseline (57.733 us; speedup 1.0000x reference)
//
#include <hip/hip_runtime.h>
#include <hip/hip_bf16.h>
#include <math.h>

typedef short bf16x8 __attribute__((ext_vector_type(8)));
typedef short shortx4 __attribute__((ext_vector_type(4)));
typedef float f32x4 __attribute__((ext_vector_type(4)));
typedef float f32x2 __attribute__((ext_vector_type(2)));
typedef unsigned short u16;

#define NT 256
#define TSTR 50      // T row stride in u16: 25 dwords, odd -> conflict-minimal
#define C1c 1e-4f
#define C2c 9e-4f

// software RNE f32->bf16 (weight quantization only; once per block)
__device__ inline u16 f2bf(float f) {
    unsigned u = __float_as_uint(f);
    return (u16)((u + 0x7FFFu + ((u >> 16) & 1u)) >> 16);
}
__device__ inline float bf2f(u16 h) { return __uint_as_float((unsigned)h << 16); }

// compiler-path f32->bf16 (RNE): adjacent casts fuse into v_cvt_pk_bf16_f32
// without the register-pinning tax of inline asm (T12/m240: asm cvt_pk -37%).
__device__ inline short bfr(float f) {
    __hip_bfloat16 h = __float2bfloat16(f);
    return __builtin_bit_cast(short, h);
}

// 64x32 tile, MFMA banded-Toeplitz separable conv (r11 structure, r11 numerics).
// r13 change: ALL inline-asm cvt_pk replaced by compiler bf16 casts.
template <bool ATOMIC>
__global__ __launch_bounds__(NT) void ssim_mfma5(
    const float* __restrict__ img1, const float* __restrict__ img2,
    const float* __restrict__ window, float* __restrict__ partials)
{
    __shared__ alignas(16) u16 T[5][64 * TSTR];  // [field][x][yhalo]
    __shared__ u16 wtab[64];                     // bf16 g at slots 20..30, zeros else
    __shared__ float wred[4];

    const int tid = threadIdx.x;
    const int x0 = blockIdx.x * 64;
    const int y0 = blockIdx.y * 32;
    const float* p1 = img1 + (size_t)blockIdx.z * (512 * 512);
    const float* p2 = img2 + (size_t)blockIdx.z * (512 * 512);

    // ---- weight table: zeros + error-feedback bf16 quantization of g ----
    if (tid < 64 && (tid < 20 || tid > 30)) wtab[tid] = 0;
    if (tid == 0) {
        float inv = 1.0f / sqrtf(window[60]);      // w2[5][5] = g5^2
        float carry = 0.f;
        for (int k = 0; k < 11; ++k) {
            float gk = window[55 + k] * inv + carry;
            u16 q = f2bf(gk);
            carry = gk - bf2f(q);
            wtab[20 + k] = q;
        }
    }
    __syncthreads();

    const int lane = tid & 63;
    const int lrow = lane & 15;
    const int lgrp = lane >> 4;
    const int wid = tid >> 6;

    // Toeplitz weight fragments (k = 8*lgrp + j; k-order cancels between frags)
    bf16x8 wB, wA;
    #pragma unroll
    for (int j = 0; j < 8; ++j) {
        int k = lgrp * 8 + j;
        wB[j] = (short)wtab[17 + k - lrow];   // pass1: g[k - n - 3]
        wA[j] = (short)wtab[20 + k - lrow];   // pass2: g[k - i]
    }
    f32x4 z4 = {0.f, 0.f, 0.f, 0.f};

    // interior: all pass-1 loads in-bounds (gx in [x0-8,x0+71], gy in [y0-5,y0+42])
    const bool interior = (x0 >= 8) && (x0 <= 440) && (y0 >= 5) && (y0 <= 469);

    // ---- pass 1: 3 row-tiles (m1 = 0,1,2), n1 = wid ----
    const int n1 = wid;
    for (int m1 = 0; m1 < 3; ++m1) {
        int gy = y0 - 5 + 16 * m1 + lrow;
        int gxb = x0 - 8 + 16 * n1 + 8 * lgrp;

        float4 A0 = make_float4(0.f,0.f,0.f,0.f), A1 = A0, B0 = A0, B1 = A0;
        if (interior) {
            const float* r1 = p1 + gy * 512 + gxb;
            const float* r2 = p2 + gy * 512 + gxb;
            A0 = *(const float4*)(r1);
            A1 = *(const float4*)(r1 + 4);
            B0 = *(const float4*)(r2);
            B1 = *(const float4*)(r2 + 4);
        } else {
            bool yok = (unsigned)gy < 512u;
            if (yok && gxb >= 0 && gxb <= 508) {
                A0 = *(const float4*)(p1 + gy * 512 + gxb);
                B0 = *(const float4*)(p2 + gy * 512 + gxb);
            }
            int gxb4 = gxb + 4;
            if (yok && gxb4 >= 0 && gxb4 <= 508) {
                A1 = *(const float4*)(p1 + gy * 512 + gxb4);
                B1 = *(const float4*)(p2 + gy * 512 + gxb4);
            }
        }
        float xa[8] = {A0.x, A0.y, A0.z, A0.w, A1.x, A1.y, A1.z, A1.w};
        float xb[8] = {B0.x, B0.y, B0.z, B0.w, B1.x, B1.y, B1.z, B1.w};

        bf16x8 fa, fb, faa, fbb, fab;
        #pragma unroll
        for (int w = 0; w < 8; ++w) {
            float a = xa[w], b = xb[w];
            fa[w]  = bfr(a);
            fb[w]  = bfr(b);
            faa[w] = bfr(a * a);
            fbb[w] = bfr(b * b);
            fab[w] = bfr(a * b);
        }

        f32x4 c0 = __builtin_amdgcn_mfma_f32_16x16x32_bf16(fa,  wB, z4, 0, 0, 0);
        f32x4 c1 = __builtin_amdgcn_mfma_f32_16x16x32_bf16(fb,  wB, z4, 0, 0, 0);
        f32x4 c2 = __builtin_amdgcn_mfma_f32_16x16x32_bf16(faa, wB, z4, 0, 0, 0);
        f32x4 c3 = __builtin_amdgcn_mfma_f32_16x16x32_bf16(fbb, wB, z4, 0, 0, 0);
        f32x4 c4 = __builtin_amdgcn_mfma_f32_16x16x32_bf16(fab, wB, z4, 0, 0, 0);

        int tx = 16 * n1 + lrow;
        int te = tx * TSTR + 16 * m1 + 4 * lgrp;
        {
            shortx4 s0 = {bfr(c0[0]), bfr(c0[1]), bfr(c0[2]), bfr(c0[3])};
            *(shortx4*)&T[0][te] = s0;
            shortx4 s1 = {bfr(c1[0]), bfr(c1[1]), bfr(c1[2]), bfr(c1[3])};
            *(shortx4*)&T[1][te] = s1;
            shortx4 s2 = {bfr(c2[0]), bfr(c2[1]), bfr(c2[2]), bfr(c2[3])};
            *(shortx4*)&T[2][te] = s2;
            shortx4 s3 = {bfr(c3[0]), bfr(c3[1]), bfr(c3[2]), bfr(c3[3])};
            *(shortx4*)&T[3][te] = s3;
            shortx4 s4 = {bfr(c4[0]), bfr(c4[1]), bfr(c4[2]), bfr(c4[3])};
            *(shortx4*)&T[4][te] = s4;
        }
    }
    __syncthreads();

    // ---- pass 2: 2 y-tiles (m2 = 0,1), n2 = wid; MFMA(wA, T) + SSIM ----
    float lsum = 0.f;
    {
        const int tx = 16 * wid + lrow;
        const int teb = tx * TSTR + 8 * lgrp;
        #pragma unroll
        for (int m2 = 0; m2 < 2; ++m2) {
            f32x4 cf[5];
            #pragma unroll
            for (int f = 0; f < 5; ++f) {
                uint4 q = *(const uint4*)&T[f][teb + 16 * m2];
                cf[f] = __builtin_amdgcn_mfma_f32_16x16x32_bf16(wA, __builtin_bit_cast(bf16x8, q), z4, 0, 0, 0);
            }
            #pragma unroll
            for (int pr = 0; pr < 2; ++pr) {
                f32x2 mu1 = {cf[0][2*pr], cf[0][2*pr+1]};
                f32x2 mu2 = {cf[1][2*pr], cf[1][2*pr+1]};
                f32x2 e11 = {cf[2][2*pr], cf[2][2*pr+1]};
                f32x2 e22 = {cf[3][2*pr], cf[3][2*pr+1]};
                f32x2 e12 = {cf[4][2*pr], cf[4][2*pr+1]};
                f32x2 m11 = mu1 * mu1, m22 = mu2 * mu2, m12 = mu1 * mu2;
                f32x2 s1  = e11 - m11;
                f32x2 s2  = e22 - m22;
                f32x2 s12 = e12 - m12;
                f32x2 num = (2.f * m12 + C1c) * (2.f * s12 + C2c);
                f32x2 den = (m11 + m22 + C1c) * (s1 + s2 + C2c);
                float v0 = num.x * __builtin_amdgcn_rcpf(den.x);
                float v1 = num.y * __builtin_amdgcn_rcpf(den.y);
                lsum += fminf(fmaxf(v0, 0.f), 1.f) + fminf(fmaxf(v1, 0.f), 1.f);
            }
        }
    }

    // ---- block reduce ----
    #pragma unroll
    for (int off = 32; off > 0; off >>= 1) lsum += __shfl_down(lsum, off);
    if ((tid & 63) == 0) wred[wid] = lsum;
    __syncthreads();
    if (tid == 0) {
        float bsum = wred[0] + wred[1] + wred[2] + wred[3];
        int bid = (blockIdx.z * gridDim.y + blockIdx.y) * gridDim.x + blockIdx.x;
        if (ATOMIC) atomicAdd(&partials[0], bsum);
        else        partials[bid] = bsum;
    }
}

__global__ void ssim_finalize(const float* __restrict__ partials, int n,
                              float* __restrict__ out, float inv_npx)
{
    __shared__ float w[4];
    float s = 0.f;
    for (int i = threadIdx.x; i < n; i += 256) s += partials[i];
    #pragma unroll
    for (int off = 32; off > 0; off >>= 1) s += __shfl_down(s, off);
    if ((threadIdx.x & 63) == 0) w[threadIdx.x >> 6] = s;
    __syncthreads();
    if (threadIdx.x == 0) {
        float total = w[0] + w[1] + w[2] + w[3];
        float loss = 1.0f - total * inv_npx;
        out[0] = fmaxf(loss, 0.0f);
    }
}

extern "C" void kernel_launch(void* const* d_in, const int* in_sizes, int n_in,
                              void* d_out, int out_size, void* d_ws, size_t ws_size,
                              hipStream_t stream) {
    const float* img1   = (const float*)d_in[0];
    const float* img2   = (const float*)d_in[1];
    const float* window = (const float*)d_in[2];
    float* out      = (float*)d_out;
    float* partials = (float*)d_ws;

    int planes = in_sizes[0] >> 18;          // 48
    dim3 grid(512 / 64, 512 / 32, planes);   // 8 x 16 x 48 = 6144 blocks
    int npart = grid.x * grid.y * grid.z;
    float inv_npx = 1.0f / (float)in_sizes[0];

    if (ws_size >= (size_t)npart * sizeof(float)) {
        ssim_mfma5<false><<<grid, NT, 0, stream>>>(img1, img2, window, partials);
        ssim_finalize<<<1, 256, 0, stream>>>(partials, npart, out, inv_npx);
    } else {
        hipMemsetAsync(d_ws, 0, sizeof(float), stream);
        ssim_mfma5<true><<<grid, NT, 0, stream>>>(img1, img2, window, partials);
        ssim_finalize<<<1, 256, 0, stream>>>(partials, 1, out, inv_npx);
    }
}